// Round 1
// baseline (203.237 us; speedup 1.0000x reference)
//
#include <hip/hip_runtime.h>

typedef __attribute__((ext_vector_type(8))) short s16x8;
typedef __attribute__((ext_vector_type(4))) short s16x4;
typedef __attribute__((ext_vector_type(4))) float fx4;

__device__ inline unsigned short f2bf(float f) {
  unsigned u = __float_as_uint(f);
  u += 0x7fffu + ((u >> 16) & 1u);
  return (unsigned short)(u >> 16);
}
__device__ inline float bf2f(unsigned short s) {
  return __uint_as_float(((unsigned)s) << 16);
}

#define GLDS16(gp, lp) \
  __builtin_amdgcn_global_load_lds((const __attribute__((address_space(1))) void*)(gp), \
                                   (__attribute__((address_space(3))) void*)(lp), 16, 0, 0)

// ---------------- cast / transpose kernels ----------------
__global__ __launch_bounds__(256) void cast_x_k(const float* __restrict__ x,
                                                unsigned short* __restrict__ xb) {
  int i = (blockIdx.x * 256 + threadIdx.x) * 8;
  fx4 a = *(const fx4*)&x[i];
  fx4 b = *(const fx4*)&x[i + 4];
  s16x8 o;
  o[0] = (short)f2bf(a[0]); o[1] = (short)f2bf(a[1]);
  o[2] = (short)f2bf(a[2]); o[3] = (short)f2bf(a[3]);
  o[4] = (short)f2bf(b[0]); o[5] = (short)f2bf(b[1]);
  o[6] = (short)f2bf(b[2]); o[7] = (short)f2bf(b[3]);
  *(s16x8*)&xb[i] = o;
}

__global__ __launch_bounds__(256) void twqkv_k(const float* __restrict__ w,
                                               unsigned short* __restrict__ wT) {
  int o = blockIdx.x * 256 + threadIdx.x;      // < 1536*512
  int j = o >> 9, kk = o & 511;
  wT[o] = f2bf(w[kk * 1536 + j]);
}

__global__ __launch_bounds__(256) void cast_wp_k(const float* __restrict__ w,
                                                 unsigned short* __restrict__ wb) {
  int o = blockIdx.x * 256 + threadIdx.x;      // < 512*512
  wb[o] = f2bf(w[o]);
}

// ---------------- GEMM: 128x128 tile, BK=32, 4 waves (2x2), 16x16x32 bf16 MFMA --------
// MODE 0: A=[32768][512] xb, BT=[1536][512] wqkvT, out -> q,k,v (bf16, split layouts)
// MODE 1: A=v + bb*4096*512, BT=weffT + bb*512*512, out -> fp32 [b n][512]
template <int MODE>
__global__ __launch_bounds__(256, 2) void gemm_k(
    const unsigned short* __restrict__ A, const unsigned short* __restrict__ BT,
    const float* __restrict__ bias,
    unsigned short* __restrict__ qo, unsigned short* __restrict__ ko,
    unsigned short* __restrict__ vo, float* __restrict__ outp) {
  __shared__ alignas(16) unsigned short As[128 * 32];
  __shared__ alignas(16) unsigned short Bs[128 * 32];
  int tid = threadIdx.x, wave = tid >> 6, lane = tid & 63;
  int l15 = lane & 15, l16 = lane >> 4;
  int wr = wave >> 1, wc = wave & 1;

  int mt, nt, bb = 0;
  if (MODE == 0) { mt = blockIdx.x / 12; nt = blockIdx.x % 12; }
  else { bb = blockIdx.x >> 7; int r = blockIdx.x & 127; mt = r >> 2; nt = r & 3; }
  const unsigned short* Ab = A + (MODE == 0 ? (size_t)0 : (size_t)bb * 4096 * 512);
  const unsigned short* Bb = BT + (MODE == 0 ? (size_t)0 : (size_t)bb * 512 * 512);
  int row0 = mt * 128, col0 = nt * 128;

  fx4 acc[4][4];
  for (int i = 0; i < 4; ++i)
    for (int j = 0; j < 4; ++j) acc[i][j] = (fx4){0.f, 0.f, 0.f, 0.f};

  // staging geometry: call c covers rows [c*64 .. c*64+64); per wave 16 rows.
  int smr = wave * 16 + (lane >> 2);       // row within 64-row group
  int skk = (lane & 3) * 8;                // k element offset (16B per lane)
  const unsigned short* agp = Ab + (size_t)(row0 + smr) * 512 + skk;
  const unsigned short* bgp = Bb + (size_t)(col0 + smr) * 512 + skk;
  unsigned short* alp = As + wave * 512;   // 1024B per wave
  unsigned short* blp = Bs + wave * 512;

  for (int kt = 0; kt < 16; ++kt) {
    int k0 = kt * 32;
    GLDS16(agp + k0, alp);
    GLDS16(agp + 64 * 512 + k0, alp + 2048);
    GLDS16(bgp + k0, blp);
    GLDS16(bgp + 64 * 512 + k0, blp + 2048);
    asm volatile("s_waitcnt vmcnt(0)" ::: "memory");
    __syncthreads();

    int kb = l16 * 8;
    s16x8 af[4], bf[4];
    for (int mi = 0; mi < 4; ++mi)
      af[mi] = *(const s16x8*)&As[(wr * 64 + mi * 16 + l15) * 32 + kb];
    for (int nj = 0; nj < 4; ++nj)
      bf[nj] = *(const s16x8*)&Bs[(wc * 64 + nj * 16 + l15) * 32 + kb];
    for (int mi = 0; mi < 4; ++mi)
      for (int nj = 0; nj < 4; ++nj)
        acc[mi][nj] = __builtin_amdgcn_mfma_f32_16x16x32_bf16(af[mi], bf[nj], acc[mi][nj], 0, 0, 0);
    __syncthreads();
  }

  int crow0 = row0 + wr * 64;
  int ccol0 = col0 + wc * 64;
  if (MODE == 0) {
    int seg = ccol0 >> 9;  // 0=q,1=k,2=v (tile never spans segments)
    for (int mi = 0; mi < 4; ++mi)
      for (int nj = 0; nj < 4; ++nj) {
        int gc = ccol0 + nj * 16 + l15;
        float bsv = bias[gc];
        for (int r = 0; r < 4; ++r) {
          int gr = crow0 + mi * 16 + l16 * 4 + r;
          unsigned short o = f2bf(acc[mi][nj][r] + bsv);
          int b_ = gr >> 12, n_ = gr & 4095;
          if (seg == 0) {
            qo[((((size_t)b_ * 8 + (gc >> 6)) * 4096 + n_) << 6) + (gc & 63)] = o;
          } else if (seg == 1) {
            int c2 = gc - 512;
            ko[((((size_t)b_ * 8 + (c2 >> 6)) * 4096 + n_) << 6) + (c2 & 63)] = o;
          } else {
            vo[((size_t)gr << 9) + (gc - 1024)] = o;
          }
        }
      }
  } else {
    for (int mi = 0; mi < 4; ++mi)
      for (int nj = 0; nj < 4; ++nj) {
        int gc = ccol0 + nj * 16 + l15;
        float bsv = bias[gc];
        for (int r = 0; r < 4; ++r) {
          int gr = crow0 + mi * 16 + l16 * 4 + r;  // row within batch
          outp[(((size_t)bb * 4096 + gr) << 9) + gc] = acc[mi][nj][r] + bsv;
        }
      }
  }
}

// ---------------- partial scores: S_part[bh][seg][d][e] = sum_{n in seg} q[n][d]*k[n][e]
__global__ __launch_bounds__(256) void scores_partial_k(const unsigned short* __restrict__ q,
                                                        const unsigned short* __restrict__ k,
                                                        float* __restrict__ sp) {
  __shared__ alignas(16) float qs[64 * 64];
  __shared__ alignas(16) float ks[64 * 64];
  int bid = blockIdx.x;            // 512 = bh*8 + seg
  int bh = bid >> 3, seg = bid & 7;
  const unsigned short* qb = q + ((size_t)bh * 4096 + seg * 512) * 64;
  const unsigned short* kb = k + ((size_t)bh * 4096 + seg * 512) * 64;
  int tid = threadIdx.x;
  int dg = tid >> 4, eg = tid & 15;
  float acc[4][4] = {{0.f}};
  for (int ch = 0; ch < 8; ++ch) {
    __syncthreads();
    for (int r = 0; r < 4; ++r) {
      int idx = r * 1024 + tid * 4;
      s16x4 qv = *(const s16x4*)&qb[ch * 4096 + idx];
      s16x4 kv = *(const s16x4*)&kb[ch * 4096 + idx];
      fx4 qf = {bf2f((unsigned short)qv[0]), bf2f((unsigned short)qv[1]),
                bf2f((unsigned short)qv[2]), bf2f((unsigned short)qv[3])};
      fx4 kf = {bf2f((unsigned short)kv[0]), bf2f((unsigned short)kv[1]),
                bf2f((unsigned short)kv[2]), bf2f((unsigned short)kv[3])};
      *(fx4*)&qs[idx] = qf;
      *(fx4*)&ks[idx] = kf;
    }
    __syncthreads();
    for (int n = 0; n < 64; ++n) {
      fx4 qv4 = *(const fx4*)&qs[n * 64 + dg * 4];
      fx4 kv4 = *(const fx4*)&ks[n * 64 + eg * 4];
      for (int i = 0; i < 4; ++i)
        for (int j = 0; j < 4; ++j) acc[i][j] += qv4[i] * kv4[j];
    }
  }
  float* o = sp + (size_t)bid * 4096;
  for (int i = 0; i < 4; ++i)
    for (int j = 0; j < 4; ++j) o[(dg * 4 + i) * 64 + eg * 4 + j] = acc[i][j];
}

// ---------------- softmax + W_effT[b][j][h*64+e] = sum_d attn[d][e] * wp[h*64+d][j]
__global__ __launch_bounds__(256) void softmax_weff_k(const float* __restrict__ sp,
                                                      const unsigned short* __restrict__ wpb,
                                                      const float* __restrict__ temp,
                                                      unsigned short* __restrict__ weffT) {
  __shared__ alignas(16) float S[64 * 64];
  __shared__ alignas(16) unsigned short wps[64 * 512];
  int bh = blockIdx.x;
  int b = bh >> 3, h = bh & 7;
  int tid = threadIdx.x;
  float tval = temp[h];
  for (int i = tid * 4; i < 4096; i += 1024) {
    fx4 s = {0.f, 0.f, 0.f, 0.f};
    for (int seg = 0; seg < 8; ++seg) {
      fx4 v4 = *(const fx4*)&sp[((size_t)(bh * 8 + seg)) * 4096 + i];
      s += v4;
    }
    s *= tval;
    *(fx4*)&S[i] = s;
  }
  for (int i = tid * 8; i < 32768; i += 2048)
    *(s16x8*)&wps[i] = *(const s16x8*)&wpb[(size_t)(h * 64) * 512 + i];
  __syncthreads();
  if (tid < 64) {
    float* row = &S[tid * 64];
    float mx = row[0];
    for (int e = 1; e < 64; ++e) mx = fmaxf(mx, row[e]);
    float sum = 0.f;
    for (int e = 0; e < 64; ++e) { float p = __expf(row[e] - mx); row[e] = p; sum += p; }
    float inv = 1.f / sum;
    for (int e = 0; e < 64; ++e) row[e] *= inv;
  }
  __syncthreads();
  int jg = tid >> 4, eg = tid & 15;
  for (int jo = 0; jo < 4; ++jo) {
    int j0 = jo * 128 + jg * 8;
    float a[4][8];
    for (int i = 0; i < 4; ++i)
      for (int j = 0; j < 8; ++j) a[i][j] = 0.f;
    for (int d = 0; d < 64; ++d) {
      fx4 at = *(const fx4*)&S[d * 64 + eg * 4];
      s16x8 wv = *(const s16x8*)&wps[d * 512 + j0];
      float wf[8];
      for (int j = 0; j < 8; ++j) wf[j] = bf2f((unsigned short)wv[j]);
      for (int i = 0; i < 4; ++i)
        for (int j = 0; j < 8; ++j) a[i][j] += at[i] * wf[j];
    }
    for (int j = 0; j < 8; ++j)
      for (int i = 0; i < 4; ++i)
        weffT[(((size_t)b * 512 + j0 + j) << 9) + h * 64 + eg * 4 + i] = f2bf(a[i][j]);
  }
}

// ---------------- host ----------------
extern "C" void kernel_launch(void* const* d_in, const int* in_sizes, int n_in,
                              void* d_out, int out_size, void* d_ws, size_t ws_size,
                              hipStream_t stream) {
  const float* x      = (const float*)d_in[0];
  const float* w_qkv  = (const float*)d_in[1];
  const float* b_qkv  = (const float*)d_in[2];
  const float* w_p    = (const float*)d_in[3];
  const float* b_p    = (const float*)d_in[4];
  const float* temp   = (const float*)d_in[5];
  float* out = (float*)d_out;
  char* ws = (char*)d_ws;

  // workspace layout (xb region reused for sp/weffT after GEMM A)
  unsigned short* xb    = (unsigned short*)(ws + 0);          // 33,554,432 B
  float*          sp    = (float*)(ws + 0);                   //  8,388,608 B (after xb dead)
  unsigned short* weffT = (unsigned short*)(ws + 8388608);    //  4,194,304 B
  unsigned short* wqkvT = (unsigned short*)(ws + 33554432);   //  1,572,864 B
  unsigned short* wpb   = (unsigned short*)(ws + 35127296);   //    524,288 B
  unsigned short* qb    = (unsigned short*)(ws + 35651584);   // 33,554,432 B
  unsigned short* kb    = (unsigned short*)(ws + 69206016);   // 33,554,432 B
  unsigned short* vb    = (unsigned short*)(ws + 102760448);  // 33,554,432 B

  cast_x_k<<<8192, 256, 0, stream>>>(x, xb);
  twqkv_k<<<3072, 256, 0, stream>>>(w_qkv, wqkvT);
  cast_wp_k<<<1024, 256, 0, stream>>>(w_p, wpb);
  gemm_k<0><<<3072, 256, 0, stream>>>(xb, wqkvT, b_qkv, qb, kb, vb, nullptr);
  scores_partial_k<<<512, 256, 0, stream>>>(qb, kb, sp);
  softmax_weff_k<<<64, 256, 0, stream>>>(sp, wpb, temp, weffT);
  gemm_k<1><<<1024, 256, 0, stream>>>(vb, weffT, b_p, nullptr, nullptr, nullptr, out);
}

// Round 3
// 180.274 us; speedup vs baseline: 1.1274x; 1.1274x over previous
//
#include <hip/hip_runtime.h>

typedef __attribute__((ext_vector_type(8))) short s16x8;
typedef __attribute__((ext_vector_type(4))) short s16x4;
typedef __attribute__((ext_vector_type(4))) float fx4;

__device__ inline unsigned short f2bf(float f) {
  unsigned u = __float_as_uint(f);
  u += 0x7fffu + ((u >> 16) & 1u);
  return (unsigned short)(u >> 16);
}
__device__ inline float bf2f(unsigned short s) {
  return __uint_as_float(((unsigned)s) << 16);
}

#define GLDS16(gp, lp) \
  __builtin_amdgcn_global_load_lds((const __attribute__((address_space(1))) void*)(gp), \
                                   (__attribute__((address_space(3))) void*)(lp), 16, 0, 0)

// ---------------- cast / transpose kernels ----------------
__global__ __launch_bounds__(256) void cast_x_k(const float* __restrict__ x,
                                                unsigned short* __restrict__ xb) {
  int i = (blockIdx.x * 256 + threadIdx.x) * 8;
  fx4 a = *(const fx4*)&x[i];
  fx4 b = *(const fx4*)&x[i + 4];
  s16x8 o;
  o[0] = (short)f2bf(a[0]); o[1] = (short)f2bf(a[1]);
  o[2] = (short)f2bf(a[2]); o[3] = (short)f2bf(a[3]);
  o[4] = (short)f2bf(b[0]); o[5] = (short)f2bf(b[1]);
  o[6] = (short)f2bf(b[2]); o[7] = (short)f2bf(b[3]);
  *(s16x8*)&xb[i] = o;
}

__global__ __launch_bounds__(256) void twqkv_k(const float* __restrict__ w,
                                               unsigned short* __restrict__ wT) {
  int o = blockIdx.x * 256 + threadIdx.x;      // < 1536*512
  int j = o >> 9, kk = o & 511;
  wT[o] = f2bf(w[kk * 1536 + j]);
}

__global__ __launch_bounds__(256) void cast_wp_k(const float* __restrict__ w,
                                                 unsigned short* __restrict__ wb) {
  int o = blockIdx.x * 256 + threadIdx.x;      // < 512*512
  wb[o] = f2bf(w[o]);
}

// ---------------- GEMM: 128x128 tile, BK=32, dbuf prefetch, 4 waves, 16x16x32 bf16 MFMA
// MODE 0: A=[32768][512] xb, BT=[1536][512] wqkvT, out -> q,k,v (bf16, split layouts)
// MODE 1: A=v + bb*4096*512, BT=weffT + bb*512*512, out -> fp32 [b n][512]
template <int MODE>
__global__ __launch_bounds__(256, 2) void gemm_k(
    const unsigned short* __restrict__ A, const unsigned short* __restrict__ BT,
    const float* __restrict__ bias,
    unsigned short* __restrict__ qo, unsigned short* __restrict__ ko,
    unsigned short* __restrict__ vo, float* __restrict__ outp) {
  __shared__ alignas(16) unsigned short As[2][128 * 32];
  __shared__ alignas(16) unsigned short Bs[2][128 * 32];
  int tid = threadIdx.x, wave = tid >> 6, lane = tid & 63;
  int l15 = lane & 15, l16 = lane >> 4;
  int wr = wave >> 1, wc = wave & 1;

  // XCD-aware bijective swizzle (nwg % 8 == 0 in both modes)
  int nwg = (MODE == 0) ? 3072 : 1024;
  int cpx = nwg >> 3;
  int bid = (blockIdx.x & 7) * cpx + (blockIdx.x >> 3);

  int mt, nt, bb = 0;
  if (MODE == 0) { mt = bid / 12; nt = bid % 12; }
  else { bb = bid >> 7; int r = bid & 127; mt = r >> 2; nt = r & 3; }
  const unsigned short* Ab = A + (MODE == 0 ? (size_t)0 : (size_t)bb * 4096 * 512);
  const unsigned short* Bb = BT + (MODE == 0 ? (size_t)0 : (size_t)bb * 512 * 512);
  int row0 = mt * 128, col0 = nt * 128;

  fx4 acc[4][4];
  for (int i = 0; i < 4; ++i)
    for (int j = 0; j < 4; ++j) acc[i][j] = (fx4){0.f, 0.f, 0.f, 0.f};

  // staging geometry: per call, a wave covers 16 rows (4 lanes x 16B per 64B row).
  int smr = wave * 16 + (lane >> 2);       // row within 64-row group
  int skk = (lane & 3) * 8;                // k element offset (16B per lane)
  const unsigned short* agp = Ab + (size_t)(row0 + smr) * 512 + skk;
  const unsigned short* bgp = Bb + (size_t)(col0 + smr) * 512 + skk;
  int ldsoff = wave * 512;                 // elements; 1024B per wave

#define STAGE(buf, kt_)                                        \
  do {                                                         \
    int k0_ = (kt_) * 32;                                      \
    GLDS16(agp + k0_, &As[buf][ldsoff]);                       \
    GLDS16(agp + 64 * 512 + k0_, &As[buf][ldsoff + 2048]);     \
    GLDS16(bgp + k0_, &Bs[buf][ldsoff]);                       \
    GLDS16(bgp + 64 * 512 + k0_, &Bs[buf][ldsoff + 2048]);     \
  } while (0)

  STAGE(0, 0);
  asm volatile("s_waitcnt vmcnt(0)" ::: "memory");
  __syncthreads();
  int cur = 0;

  for (int kt = 0; kt < 16; ++kt) {
    if (kt < 15) STAGE(cur ^ 1, kt + 1);   // prefetch overlaps current compute

    int kb = l16 * 8;
    s16x8 af[4], bf[4];
    for (int mi = 0; mi < 4; ++mi)
      af[mi] = *(const s16x8*)&As[cur][(wr * 64 + mi * 16 + l15) * 32 + kb];
    for (int nj = 0; nj < 4; ++nj)
      bf[nj] = *(const s16x8*)&Bs[cur][(wc * 64 + nj * 16 + l15) * 32 + kb];
    for (int mi = 0; mi < 4; ++mi)
      for (int nj = 0; nj < 4; ++nj)
        acc[mi][nj] = __builtin_amdgcn_mfma_f32_16x16x32_bf16(af[mi], bf[nj], acc[mi][nj], 0, 0, 0);

    // barrier (with vmcnt(0) drain) AFTER compute: prefetch in flight during
    // ds_read+MFMA; next buffer guaranteed ready past here.
    asm volatile("s_waitcnt vmcnt(0)" ::: "memory");
    __syncthreads();
    cur ^= 1;
  }
#undef STAGE

  int crow0 = row0 + wr * 64;
  int ccol0 = col0 + wc * 64;
  if (MODE == 0) {
    int seg = ccol0 >> 9;  // 0=q,1=k,2=v (tile never spans segments)
    for (int mi = 0; mi < 4; ++mi)
      for (int nj = 0; nj < 4; ++nj) {
        int gc = ccol0 + nj * 16 + l15;
        float bsv = bias[gc];
        for (int r = 0; r < 4; ++r) {
          int gr = crow0 + mi * 16 + l16 * 4 + r;
          unsigned short o = f2bf(acc[mi][nj][r] + bsv);
          int b_ = gr >> 12, n_ = gr & 4095;
          if (seg == 0) {
            qo[((((size_t)b_ * 8 + (gc >> 6)) * 4096 + n_) << 6) + (gc & 63)] = o;
          } else if (seg == 1) {
            int c2 = gc - 512;
            ko[((((size_t)b_ * 8 + (c2 >> 6)) * 4096 + n_) << 6) + (c2 & 63)] = o;
          } else {
            vo[((size_t)gr << 9) + (gc - 1024)] = o;
          }
        }
      }
  } else {
    for (int mi = 0; mi < 4; ++mi)
      for (int nj = 0; nj < 4; ++nj) {
        int gc = ccol0 + nj * 16 + l15;
        float bsv = bias[gc];
        for (int r = 0; r < 4; ++r) {
          int gr = crow0 + mi * 16 + l16 * 4 + r;  // row within batch
          outp[(((size_t)bb * 4096 + gr) << 9) + gc] = acc[mi][nj][r] + bsv;
        }
      }
  }
}

// ---------------- partial scores: S_part[bh][seg][d][e] = sum_{n in seg} q[n][d]*k[n][e]
__global__ __launch_bounds__(256) void scores_partial_k(const unsigned short* __restrict__ q,
                                                        const unsigned short* __restrict__ k,
                                                        float* __restrict__ sp) {
  __shared__ alignas(16) float qs[64 * 64];
  __shared__ alignas(16) float ks[64 * 64];
  int bid = blockIdx.x;            // 512 = bh*8 + seg
  int bh = bid >> 3, seg = bid & 7;
  const unsigned short* qb = q + ((size_t)bh * 4096 + seg * 512) * 64;
  const unsigned short* kb = k + ((size_t)bh * 4096 + seg * 512) * 64;
  int tid = threadIdx.x;
  int dg = tid >> 4, eg = tid & 15;
  float acc[4][4] = {{0.f}};
  for (int ch = 0; ch < 8; ++ch) {
    __syncthreads();
    for (int r = 0; r < 4; ++r) {
      int idx = r * 1024 + tid * 4;
      s16x4 qv = *(const s16x4*)&qb[ch * 4096 + idx];
      s16x4 kv = *(const s16x4*)&kb[ch * 4096 + idx];
      fx4 qf = {bf2f((unsigned short)qv[0]), bf2f((unsigned short)qv[1]),
                bf2f((unsigned short)qv[2]), bf2f((unsigned short)qv[3])};
      fx4 kf = {bf2f((unsigned short)kv[0]), bf2f((unsigned short)kv[1]),
                bf2f((unsigned short)kv[2]), bf2f((unsigned short)kv[3])};
      *(fx4*)&qs[idx] = qf;
      *(fx4*)&ks[idx] = kf;
    }
    __syncthreads();
    for (int n = 0; n < 64; ++n) {
      fx4 qv4 = *(const fx4*)&qs[n * 64 + dg * 4];
      fx4 kv4 = *(const fx4*)&ks[n * 64 + eg * 4];
      for (int i = 0; i < 4; ++i)
        for (int j = 0; j < 4; ++j) acc[i][j] += qv4[i] * kv4[j];
    }
  }
  float* o = sp + (size_t)bid * 4096;
  for (int i = 0; i < 4; ++i)
    for (int j = 0; j < 4; ++j) o[(dg * 4 + i) * 64 + eg * 4 + j] = acc[i][j];
}

// ---------------- softmax + W_effT[b][j][h*64+e] = sum_d attn[d][e] * wp[h*64+d][j]
// grid 256: block = bh*4 + jblk, each handles 128 output j-columns
__global__ __launch_bounds__(256) void softmax_weff_k(const float* __restrict__ sp,
                                                      const unsigned short* __restrict__ wpb,
                                                      const float* __restrict__ temp,
                                                      unsigned short* __restrict__ weffT) {
  __shared__ alignas(16) float S[64 * 64];
  __shared__ alignas(16) unsigned short wps[64 * 128];
  int bh = blockIdx.x >> 2, jblk = blockIdx.x & 3;
  int b = bh >> 3, h = bh & 7;
  int tid = threadIdx.x;
  float tval = temp[h];
  for (int i = tid * 4; i < 4096; i += 1024) {
    fx4 s = {0.f, 0.f, 0.f, 0.f};
    for (int seg = 0; seg < 8; ++seg) {
      fx4 v4 = *(const fx4*)&sp[((size_t)(bh * 8 + seg)) * 4096 + i];
      s += v4;
    }
    s *= tval;
    *(fx4*)&S[i] = s;
  }
  // stage wp slice: rows h*64..h*64+63, cols jblk*128..+128
  for (int i = tid * 8; i < 8192; i += 2048) {
    int d = i >> 7, c = i & 127;
    *(s16x8*)&wps[i] = *(const s16x8*)&wpb[(size_t)(h * 64 + d) * 512 + jblk * 128 + c];
  }
  __syncthreads();
  if (tid < 64) {
    float* row = &S[tid * 64];
    float mx = row[0];
    for (int e = 1; e < 64; ++e) mx = fmaxf(mx, row[e]);
    float sum = 0.f;
    for (int e = 0; e < 64; ++e) { float p = __expf(row[e] - mx); row[e] = p; sum += p; }
    float inv = 1.f / sum;
    for (int e = 0; e < 64; ++e) row[e] *= inv;
  }
  __syncthreads();
  int jg = tid >> 4, eg = tid & 15;   // jg: 0..15 -> 8 j each; eg: 0..15 -> 4 e each
  int j0 = jg * 8;                    // within 128-col slice
  float a[4][8];
  for (int i = 0; i < 4; ++i)
    for (int j = 0; j < 8; ++j) a[i][j] = 0.f;
  for (int d = 0; d < 64; ++d) {
    fx4 at = *(const fx4*)&S[d * 64 + eg * 4];
    s16x8 wv = *(const s16x8*)&wps[d * 128 + j0];
    float wf[8];
    for (int j = 0; j < 8; ++j) wf[j] = bf2f((unsigned short)wv[j]);
    for (int i = 0; i < 4; ++i)
      for (int j = 0; j < 8; ++j) a[i][j] += at[i] * wf[j];
  }
  int jglob = jblk * 128 + j0;
  for (int j = 0; j < 8; ++j)
    for (int i = 0; i < 4; ++i)
      weffT[(((size_t)b * 512 + jglob + j) << 9) + h * 64 + eg * 4 + i] = f2bf(a[i][j]);
}

// ---------------- host ----------------
extern "C" void kernel_launch(void* const* d_in, const int* in_sizes, int n_in,
                              void* d_out, int out_size, void* d_ws, size_t ws_size,
                              hipStream_t stream) {
  const float* x      = (const float*)d_in[0];
  const float* w_qkv  = (const float*)d_in[1];
  const float* b_qkv  = (const float*)d_in[2];
  const float* w_p    = (const float*)d_in[3];
  const float* b_p    = (const float*)d_in[4];
  const float* temp   = (const float*)d_in[5];
  float* out = (float*)d_out;
  char* ws = (char*)d_ws;

  // workspace layout (xb region reused for sp/weffT after GEMM A)
  unsigned short* xb    = (unsigned short*)(ws + 0);          // 33,554,432 B
  float*          sp    = (float*)(ws + 0);                   //  8,388,608 B (after xb dead)
  unsigned short* weffT = (unsigned short*)(ws + 8388608);    //  4,194,304 B
  unsigned short* wqkvT = (unsigned short*)(ws + 33554432);   //  1,572,864 B
  unsigned short* wpb   = (unsigned short*)(ws + 35127296);   //    524,288 B
  unsigned short* qb    = (unsigned short*)(ws + 35651584);   // 33,554,432 B
  unsigned short* kb    = (unsigned short*)(ws + 69206016);   // 33,554,432 B
  unsigned short* vb    = (unsigned short*)(ws + 102760448);  // 33,554,432 B

  cast_x_k<<<8192, 256, 0, stream>>>(x, xb);
  twqkv_k<<<3072, 256, 0, stream>>>(w_qkv, wqkvT);
  cast_wp_k<<<1024, 256, 0, stream>>>(w_p, wpb);
  gemm_k<0><<<3072, 256, 0, stream>>>(xb, wqkvT, b_qkv, qb, kb, vb, nullptr);
  scores_partial_k<<<512, 256, 0, stream>>>(qb, kb, sp);
  softmax_weff_k<<<256, 256, 0, stream>>>(sp, wpb, temp, weffT);
  gemm_k<1><<<1024, 256, 0, stream>>>(vb, weffT, b_p, nullptr, nullptr, nullptr, out);
}

// Round 4
// 176.507 us; speedup vs baseline: 1.1514x; 1.0213x over previous
//
#include <hip/hip_runtime.h>

typedef __attribute__((ext_vector_type(8))) short s16x8;
typedef __attribute__((ext_vector_type(4))) short s16x4;
typedef __attribute__((ext_vector_type(4))) float fx4;

__device__ inline unsigned short f2bf(float f) {
  unsigned u = __float_as_uint(f);
  u += 0x7fffu + ((u >> 16) & 1u);
  return (unsigned short)(u >> 16);
}
__device__ inline float bf2f(unsigned short s) {
  return __uint_as_float(((unsigned)s) << 16);
}

#define GLDS16(gp, lp) \
  __builtin_amdgcn_global_load_lds((const __attribute__((address_space(1))) void*)(gp), \
                                   (__attribute__((address_space(3))) void*)(lp), 16, 0, 0)

// ---------------- cast / transpose kernels ----------------
__global__ __launch_bounds__(256) void cast_x_k(const float* __restrict__ x,
                                                unsigned short* __restrict__ xb) {
  int i = (blockIdx.x * 256 + threadIdx.x) * 8;
  fx4 a = *(const fx4*)&x[i];
  fx4 b = *(const fx4*)&x[i + 4];
  s16x8 o;
  o[0] = (short)f2bf(a[0]); o[1] = (short)f2bf(a[1]);
  o[2] = (short)f2bf(a[2]); o[3] = (short)f2bf(a[3]);
  o[4] = (short)f2bf(b[0]); o[5] = (short)f2bf(b[1]);
  o[6] = (short)f2bf(b[2]); o[7] = (short)f2bf(b[3]);
  *(s16x8*)&xb[i] = o;
}

__global__ __launch_bounds__(256) void twqkv_k(const float* __restrict__ w,
                                               unsigned short* __restrict__ wT) {
  int o = blockIdx.x * 256 + threadIdx.x;      // < 1536*512
  int j = o >> 9, kk = o & 511;
  wT[o] = f2bf(w[kk * 1536 + j]);
}

__global__ __launch_bounds__(256) void cast_wp_k(const float* __restrict__ w,
                                                 unsigned short* __restrict__ wb) {
  int o = blockIdx.x * 256 + threadIdx.x;      // < 512*512
  wb[o] = f2bf(w[o]);
}

// ---------------- GEMM: 128x128 tile, BK=32, depth-2 counted-vmcnt pipeline,
// 4 waves (2x2), 16x16x32 bf16 MFMA, LDS chunk-XOR swizzle (linear GLDS dest,
// pre-swizzled global source, XOR on read -- rule 21).
// MODE 0: A=[32768][512] xb, BT=[1536][512] wqkvT, out -> q,k,v (bf16, split layouts)
// MODE 1: A=v + bb*4096*512, BT=weffT + bb*512*512, out -> fp32 [b n][512]
template <int MODE>
__global__ __launch_bounds__(256, 2) void gemm_k(
    const unsigned short* __restrict__ A, const unsigned short* __restrict__ BT,
    const float* __restrict__ bias,
    unsigned short* __restrict__ qo, unsigned short* __restrict__ ko,
    unsigned short* __restrict__ vo, float* __restrict__ outp) {
  __shared__ alignas(16) unsigned short As[2][128 * 32];
  __shared__ alignas(16) unsigned short Bs[2][128 * 32];
  int tid = threadIdx.x, wave = tid >> 6, lane = tid & 63;
  int l15 = lane & 15, l16 = lane >> 4;
  int wr = wave >> 1, wc = wave & 1;

  // XCD-aware bijective swizzle (nwg % 8 == 0 in both modes)
  int nwg = (MODE == 0) ? 3072 : 1024;
  int cpx = nwg >> 3;
  int bid = (blockIdx.x & 7) * cpx + (blockIdx.x >> 3);

  int mt, nt, bb = 0;
  if (MODE == 0) { mt = bid / 12; nt = bid % 12; }
  else { bb = bid >> 7; int r = bid & 127; mt = r >> 2; nt = r & 3; }
  const unsigned short* Ab = A + (MODE == 0 ? (size_t)0 : (size_t)bb * 4096 * 512);
  const unsigned short* Bb = BT + (MODE == 0 ? (size_t)0 : (size_t)bb * 512 * 512);
  int row0 = mt * 128, col0 = nt * 128;

  fx4 acc[4][4];
  for (int i = 0; i < 4; ++i)
    for (int j = 0; j < 4; ++j) acc[i][j] = (fx4){0.f, 0.f, 0.f, 0.f};

  // Staging: wave covers 16 rows per GLDS call (4 lanes x 16B per 64B row).
  // Source chunk pre-swizzled: lane loads global chunk (l&3)^g, g=(l>>3)&3
  // = (row mod 16)>>1 & 3, so LDS pos p of row R holds global chunk p^g(R).
  int smr = wave * 16 + (lane >> 2);       // row within 64-row group
  int skk = (((lane & 3) ^ ((lane >> 3) & 3))) * 8;  // swizzled k-chunk offset
  const unsigned short* agp = Ab + (size_t)(row0 + smr) * 512 + skk;
  const unsigned short* bgp = Bb + (size_t)(col0 + smr) * 512 + skk;
  int ldsoff = wave * 512;                 // elements; 1024B per wave

#define STAGE(buf, kt_)                                        \
  do {                                                         \
    int k0_ = (kt_) * 32;                                      \
    GLDS16(agp + k0_, &As[buf][ldsoff]);                       \
    GLDS16(agp + 64 * 512 + k0_, &As[buf][ldsoff + 2048]);     \
    GLDS16(bgp + k0_, &Bs[buf][ldsoff]);                       \
    GLDS16(bgp + 64 * 512 + k0_, &Bs[buf][ldsoff + 2048]);     \
  } while (0)

  STAGE(0, 0);
  STAGE(1, 1);                             // depth-2 prefetch: 8 loads in flight

  // read-side swizzle: want global chunk c at row R -> LDS pos c ^ g(R);
  // rows here are base+l15 with base % 16 == 0, so g = (l15>>1)&3.
  int g = (l15 >> 1) & 3;
  int pa = (l16 ^ g) << 3;                 // element offset of swizzled chunk

  for (int kt = 0; kt < 16; ++kt) {
    // counted vmcnt: oldest 4 loads (tile kt) done; 4 (tile kt+1) stay in flight
    if (kt < 15) asm volatile("s_waitcnt vmcnt(4)" ::: "memory");
    else         asm volatile("s_waitcnt vmcnt(0)" ::: "memory");
    __builtin_amdgcn_s_barrier();          // raw: no implicit drain

    int cur = kt & 1;
    s16x8 af[4], bf[4];
    for (int mi = 0; mi < 4; ++mi)
      af[mi] = *(const s16x8*)&As[cur][(wr * 64 + mi * 16 + l15) * 32 + pa];
    for (int nj = 0; nj < 4; ++nj)
      bf[nj] = *(const s16x8*)&Bs[cur][(wc * 64 + nj * 16 + l15) * 32 + pa];
    for (int mi = 0; mi < 4; ++mi)
      for (int nj = 0; nj < 4; ++nj)
        acc[mi][nj] = __builtin_amdgcn_mfma_f32_16x16x32_bf16(af[mi], bf[nj], acc[mi][nj], 0, 0, 0);

    // all lanes' ds_reads landed in VGPRs -> safe to overwrite this buffer
    asm volatile("s_waitcnt lgkmcnt(0)" ::: "memory");
    __builtin_amdgcn_s_barrier();
    if (kt < 14) STAGE(cur, kt + 2);       // refill just-freed buffer
  }
#undef STAGE

  int crow0 = row0 + wr * 64;
  int ccol0 = col0 + wc * 64;
  if (MODE == 0) {
    int seg = ccol0 >> 9;  // 0=q,1=k,2=v (tile never spans segments)
    for (int mi = 0; mi < 4; ++mi)
      for (int nj = 0; nj < 4; ++nj) {
        int gc = ccol0 + nj * 16 + l15;
        float bsv = bias[gc];
        for (int r = 0; r < 4; ++r) {
          int gr = crow0 + mi * 16 + l16 * 4 + r;
          unsigned short o = f2bf(acc[mi][nj][r] + bsv);
          int b_ = gr >> 12, n_ = gr & 4095;
          if (seg == 0) {
            qo[((((size_t)b_ * 8 + (gc >> 6)) * 4096 + n_) << 6) + (gc & 63)] = o;
          } else if (seg == 1) {
            int c2 = gc - 512;
            ko[((((size_t)b_ * 8 + (c2 >> 6)) * 4096 + n_) << 6) + (c2 & 63)] = o;
          } else {
            vo[((size_t)gr << 9) + (gc - 1024)] = o;
          }
        }
      }
  } else {
    for (int mi = 0; mi < 4; ++mi)
      for (int nj = 0; nj < 4; ++nj) {
        int gc = ccol0 + nj * 16 + l15;
        float bsv = bias[gc];
        for (int r = 0; r < 4; ++r) {
          int gr = crow0 + mi * 16 + l16 * 4 + r;  // row within batch
          outp[(((size_t)bb * 4096 + gr) << 9) + gc] = acc[mi][nj][r] + bsv;
        }
      }
  }
}

// ---------------- partial scores: S_part[bh][seg][d][e] = sum_{n in seg} q[n][d]*k[n][e]
__global__ __launch_bounds__(256) void scores_partial_k(const unsigned short* __restrict__ q,
                                                        const unsigned short* __restrict__ k,
                                                        float* __restrict__ sp) {
  __shared__ alignas(16) float qs[64 * 64];
  __shared__ alignas(16) float ks[64 * 64];
  int bid = blockIdx.x;            // 512 = bh*8 + seg
  int bh = bid >> 3, seg = bid & 7;
  const unsigned short* qb = q + ((size_t)bh * 4096 + seg * 512) * 64;
  const unsigned short* kb = k + ((size_t)bh * 4096 + seg * 512) * 64;
  int tid = threadIdx.x;
  int dg = tid >> 4, eg = tid & 15;
  float acc[4][4] = {{0.f}};
  for (int ch = 0; ch < 8; ++ch) {
    __syncthreads();
    for (int r = 0; r < 4; ++r) {
      int idx = r * 1024 + tid * 4;
      s16x4 qv = *(const s16x4*)&qb[ch * 4096 + idx];
      s16x4 kv = *(const s16x4*)&kb[ch * 4096 + idx];
      fx4 qf = {bf2f((unsigned short)qv[0]), bf2f((unsigned short)qv[1]),
                bf2f((unsigned short)qv[2]), bf2f((unsigned short)qv[3])};
      fx4 kf = {bf2f((unsigned short)kv[0]), bf2f((unsigned short)kv[1]),
                bf2f((unsigned short)kv[2]), bf2f((unsigned short)kv[3])};
      *(fx4*)&qs[idx] = qf;
      *(fx4*)&ks[idx] = kf;
    }
    __syncthreads();
    for (int n = 0; n < 64; ++n) {
      fx4 qv4 = *(const fx4*)&qs[n * 64 + dg * 4];
      fx4 kv4 = *(const fx4*)&ks[n * 64 + eg * 4];
      for (int i = 0; i < 4; ++i)
        for (int j = 0; j < 4; ++j) acc[i][j] += qv4[i] * kv4[j];
    }
  }
  float* o = sp + (size_t)bid * 4096;
  for (int i = 0; i < 4; ++i)
    for (int j = 0; j < 4; ++j) o[(dg * 4 + i) * 64 + eg * 4 + j] = acc[i][j];
}

// ---------------- softmax + W_effT[b][j][h*64+e] = sum_d attn[d][e] * wp[h*64+d][j]
// grid 256: block = bh*4 + jblk, each handles 128 output j-columns
__global__ __launch_bounds__(256) void softmax_weff_k(const float* __restrict__ sp,
                                                      const unsigned short* __restrict__ wpb,
                                                      const float* __restrict__ temp,
                                                      unsigned short* __restrict__ weffT) {
  __shared__ alignas(16) float S[64 * 64];
  __shared__ alignas(16) unsigned short wps[64 * 128];
  int bh = blockIdx.x >> 2, jblk = blockIdx.x & 3;
  int b = bh >> 3, h = bh & 7;
  int tid = threadIdx.x;
  float tval = temp[h];
  for (int i = tid * 4; i < 4096; i += 1024) {
    fx4 s = {0.f, 0.f, 0.f, 0.f};
    for (int seg = 0; seg < 8; ++seg) {
      fx4 v4 = *(const fx4*)&sp[((size_t)(bh * 8 + seg)) * 4096 + i];
      s += v4;
    }
    s *= tval;
    *(fx4*)&S[i] = s;
  }
  // stage wp slice: rows h*64..h*64+63, cols jblk*128..+128
  for (int i = tid * 8; i < 8192; i += 2048) {
    int d = i >> 7, c = i & 127;
    *(s16x8*)&wps[i] = *(const s16x8*)&wpb[(size_t)(h * 64 + d) * 512 + jblk * 128 + c];
  }
  __syncthreads();
  if (tid < 64) {
    float* row = &S[tid * 64];
    float mx = row[0];
    for (int e = 1; e < 64; ++e) mx = fmaxf(mx, row[e]);
    float sum = 0.f;
    for (int e = 0; e < 64; ++e) { float p = __expf(row[e] - mx); row[e] = p; sum += p; }
    float inv = 1.f / sum;
    for (int e = 0; e < 64; ++e) row[e] *= inv;
  }
  __syncthreads();
  int jg = tid >> 4, eg = tid & 15;   // jg: 0..15 -> 8 j each; eg: 0..15 -> 4 e each
  int j0 = jg * 8;                    // within 128-col slice
  float a[4][8];
  for (int i = 0; i < 4; ++i)
    for (int j = 0; j < 8; ++j) a[i][j] = 0.f;
  for (int d = 0; d < 64; ++d) {
    fx4 at = *(const fx4*)&S[d * 64 + eg * 4];
    s16x8 wv = *(const s16x8*)&wps[d * 128 + j0];
    float wf[8];
    for (int j = 0; j < 8; ++j) wf[j] = bf2f((unsigned short)wv[j]);
    for (int i = 0; i < 4; ++i)
      for (int j = 0; j < 8; ++j) a[i][j] += at[i] * wf[j];
  }
  int jglob = jblk * 128 + j0;
  for (int j = 0; j < 8; ++j)
    for (int i = 0; i < 4; ++i)
      weffT[(((size_t)b * 512 + jglob + j) << 9) + h * 64 + eg * 4 + i] = f2bf(a[i][j]);
}

// ---------------- host ----------------
extern "C" void kernel_launch(void* const* d_in, const int* in_sizes, int n_in,
                              void* d_out, int out_size, void* d_ws, size_t ws_size,
                              hipStream_t stream) {
  const float* x      = (const float*)d_in[0];
  const float* w_qkv  = (const float*)d_in[1];
  const float* b_qkv  = (const float*)d_in[2];
  const float* w_p    = (const float*)d_in[3];
  const float* b_p    = (const float*)d_in[4];
  const float* temp   = (const float*)d_in[5];
  float* out = (float*)d_out;
  char* ws = (char*)d_ws;

  // workspace layout (xb region reused for sp/weffT after GEMM A)
  unsigned short* xb    = (unsigned short*)(ws + 0);          // 33,554,432 B
  float*          sp    = (float*)(ws + 0);                   //  8,388,608 B (after xb dead)
  unsigned short* weffT = (unsigned short*)(ws + 8388608);    //  4,194,304 B
  unsigned short* wqkvT = (unsigned short*)(ws + 33554432);   //  1,572,864 B
  unsigned short* wpb   = (unsigned short*)(ws + 35127296);   //    524,288 B
  unsigned short* qb    = (unsigned short*)(ws + 35651584);   // 33,554,432 B
  unsigned short* kb    = (unsigned short*)(ws + 69206016);   // 33,554,432 B
  unsigned short* vb    = (unsigned short*)(ws + 102760448);  // 33,554,432 B

  cast_x_k<<<8192, 256, 0, stream>>>(x, xb);
  twqkv_k<<<3072, 256, 0, stream>>>(w_qkv, wqkvT);
  cast_wp_k<<<1024, 256, 0, stream>>>(w_p, wpb);
  gemm_k<0><<<3072, 256, 0, stream>>>(xb, wqkvT, b_qkv, qb, kb, vb, nullptr);
  scores_partial_k<<<512, 256, 0, stream>>>(qb, kb, sp);
  softmax_weff_k<<<256, 256, 0, stream>>>(sp, wpb, temp, weffT);
  gemm_k<1><<<1024, 256, 0, stream>>>(vb, weffT, b_p, nullptr, nullptr, nullptr, out);
}